// Round 6
// baseline (373.179 us; speedup 1.0000x reference)
//
#include <hip/hip_runtime.h>
#include <stdint.h>

#define DIM   2048
#define NSLOT 64
#define MDIM  512
#define TINV  10.0f

typedef __attribute__((ext_vector_type(4))) float     f32x4;
typedef __attribute__((ext_vector_type(8))) _Float16  half8;
typedef __attribute__((ext_vector_type(4))) unsigned int u32x4;

#define MFMA16(a,b,c) __builtin_amdgcn_mfma_f32_16x16x32_f16((a),(b),(c),0,0,0)

// ---------------------------------------------------------------------------
// ws layout (bytes), total ~934 KB:
//   W2h  [80][2048] f16 : rows 0-63 = memory@key_w, row 64 = gate_w[:2048], 65-79 = 0
//   W2l  [80][2048] f16 : fp16 residual of the above (2-way split)
//   W3T  [2048][64] f16 : W3T[d][n] = sum_m memory[n][m]*value_w[d][m]
//   h    [64] f32       : h[n] = sum_d W3[n][d]*gate_w[DIM+d]
//   tpart[8][512] f32
// ---------------------------------------------------------------------------
#define OFF_W2H   0
#define OFF_W2L   327680
#define OFF_W3T   655360
#define OFF_H     917504
#define OFF_TPART 917760

// ============================ prep kernels =================================
// (byte-identical to rounds 2/4/5)

__global__ __launch_bounds__(256) void prep_w2(
    const float* __restrict__ memory, const float* __restrict__ key_w,
    const float* __restrict__ gate_w, _Float16* __restrict__ W2h,
    _Float16* __restrict__ W2l)
{
    const int tid = threadIdx.x;
    const int c = blockIdx.x;      // k-chunk of 256
    const int g = blockIdx.y;      // 0..7 slot groups, 8 = gate row + zero rows
    const int k = c * 256 + tid;

    if (g == 8) {
        float v = gate_w[k];
        _Float16 ph = (_Float16)v;
        _Float16 pl = (_Float16)(v - (float)ph);
        W2h[(size_t)64 * DIM + k] = ph;
        W2l[(size_t)64 * DIM + k] = pl;
        for (int r = 65; r < 80; ++r) {
            W2h[(size_t)r * DIM + k] = (_Float16)0.f;
            W2l[(size_t)r * DIM + k] = (_Float16)0.f;
        }
        return;
    }

    __shared__ __align__(16) float mem_s[8 * MDIM];
    for (int i = tid; i < 8 * MDIM; i += 256)
        mem_s[i] = memory[g * 8 * MDIM + i];
    __syncthreads();

    const f32x4* ms4 = (const f32x4*)mem_s;
    float acc[8] = {};
    for (int m4 = 0; m4 < MDIM / 4; ++m4) {
        const float kw0 = key_w[(size_t)(m4 * 4 + 0) * DIM + k];
        const float kw1 = key_w[(size_t)(m4 * 4 + 1) * DIM + k];
        const float kw2 = key_w[(size_t)(m4 * 4 + 2) * DIM + k];
        const float kw3 = key_w[(size_t)(m4 * 4 + 3) * DIM + k];
        #pragma unroll
        for (int i = 0; i < 8; ++i) {
            const f32x4 mv = ms4[i * (MDIM / 4) + m4];
            acc[i] = fmaf(mv.x, kw0, acc[i]);
            acc[i] = fmaf(mv.y, kw1, acc[i]);
            acc[i] = fmaf(mv.z, kw2, acc[i]);
            acc[i] = fmaf(mv.w, kw3, acc[i]);
        }
    }
    #pragma unroll
    for (int i = 0; i < 8; ++i) {
        float v = acc[i];
        _Float16 ph = (_Float16)v;
        _Float16 pl = (_Float16)(v - (float)ph);
        W2h[(size_t)(g * 8 + i) * DIM + k] = ph;
        W2l[(size_t)(g * 8 + i) * DIM + k] = pl;
    }
}

__global__ __launch_bounds__(256) void prep_w3t(
    const float* __restrict__ memory, const float* __restrict__ value_w,
    _Float16* __restrict__ W3T)
{
    const int tid = threadIdx.x;
    const int c = blockIdx.x;      // d-chunk of 256
    const int g = blockIdx.y;      // slot group of 8
    const int d = c * 256 + tid;

    __shared__ __align__(16) float mem_s[8 * MDIM];
    for (int i = tid; i < 8 * MDIM; i += 256)
        mem_s[i] = memory[g * 8 * MDIM + i];
    __syncthreads();

    const f32x4* ms4 = (const f32x4*)mem_s;
    const f32x4* vp = (const f32x4*)(value_w + (size_t)d * MDIM);
    float acc[8] = {};
    for (int m4 = 0; m4 < MDIM / 4; ++m4) {
        const f32x4 v = vp[m4];
        #pragma unroll
        for (int i = 0; i < 8; ++i) {
            const f32x4 mv = ms4[i * (MDIM / 4) + m4];
            acc[i] = fmaf(mv.x, v.x, acc[i]);
            acc[i] = fmaf(mv.y, v.y, acc[i]);
            acc[i] = fmaf(mv.z, v.z, acc[i]);
            acc[i] = fmaf(mv.w, v.w, acc[i]);
        }
    }
    #pragma unroll
    for (int i = 0; i < 8; ++i)
        W3T[(size_t)d * NSLOT + g * 8 + i] = (_Float16)acc[i];
}

__global__ __launch_bounds__(256) void prep_t(
    const float* __restrict__ value_w, const float* __restrict__ gate_w,
    float* __restrict__ tpart)
{
    const int b = blockIdx.x;      // d-chunk of 256
    const int tid = threadIdx.x;
    float a0 = 0.f, a1 = 0.f;
    for (int d = b * 256; d < b * 256 + 256; ++d) {
        const float gv = gate_w[DIM + d];
        a0 = fmaf(value_w[(size_t)d * MDIM + tid], gv, a0);
        a1 = fmaf(value_w[(size_t)d * MDIM + tid + 256], gv, a1);
    }
    tpart[b * 512 + tid] = a0;
    tpart[b * 512 + tid + 256] = a1;
}

__global__ __launch_bounds__(512) void prep_h(
    const float* __restrict__ memory, const float* __restrict__ tpart,
    float* __restrict__ h)
{
    __shared__ float ts[512];
    const int tid = threadIdx.x;
    float s = 0.f;
    #pragma unroll
    for (int b = 0; b < 8; ++b) s += tpart[b * 512 + tid];
    ts[tid] = s;
    __syncthreads();
    const int lane = tid & 63, w = tid >> 6;
    #pragma unroll
    for (int q = 0; q < 8; ++q) {
        const int n = w * 8 + q;
        float p = 0.f;
        for (int m = lane; m < MDIM; m += 64)
            p = fmaf(memory[(size_t)n * MDIM + m], ts[m], p);
        #pragma unroll
        for (int off = 32; off; off >>= 1) p += __shfl_xor(p, off);
        if (lane == 0) h[n] = p;
    }
}

// ============================ fused kernel =================================
// Phase A = round-2 scores_kernel VERBATIM (4 waves, 256 threads, 64 rows,
// same staging geometry) except attn/gate go to wave-local LDS instead of
// global. Phase B = round-5 retrieve_kernel3 VERBATIM (swapped-operand MFMA,
// float4 mix) except A-frags/gate come from the wave-local LDS tile and each
// wave covers the full 2048 d for its 16 rows. No other changes vs proven
// kernels; handoff indices are identical to the validated global-attn path.

__global__ __launch_bounds__(256) void fused_kernel(
    const float* __restrict__ x,
    const _Float16* __restrict__ W2h, const _Float16* __restrict__ W2l,
    const _Float16* __restrict__ W3T,
    const float* __restrict__ h, const float* __restrict__ gate_b,
    float* __restrict__ out)
{
    __shared__ __align__(16) _Float16 w2s[2 * 80 * 128];   // 40 KB
    __shared__ __align__(16) _Float16 attn_s[4][16][72];   // 9 KB
    __shared__ float gate_s[4][16];

    const int tid  = threadIdx.x;
    const int lane = tid & 63;
    const int w    = tid >> 6;          // wave = m-tile 0..3
    const int arow = lane & 15;         // A-row / B-row (lane&15)
    const int kg   = lane >> 4;         // k-group
    const size_t row0 = (size_t)blockIdx.x * 64;

    f32x4 acc[5];
    {   f32x4 z = {0.f, 0.f, 0.f, 0.f};
        #pragma unroll
        for (int t = 0; t < 5; ++t) acc[t] = z; }

    const float* xrow = x + (row0 + w * 16 + arow) * DIM + kg * 8;

    for (int ch = 0; ch < 16; ++ch) {
        // ---- stage W2 chunk (hi+lo) into LDS, swizzled dest ----
        u32x4 wg[10];
        #pragma unroll
        for (int i = 0; i < 10; ++i) {
            const int lvl = (i >= 5) ? 1 : 0;             // uniform per unrolled i
            const int gg = tid + i * 256 - lvl * 1280;    // granule within level
            const int rr = gg >> 4, gk = gg & 15;
            const _Float16* src = (lvl ? W2l : W2h) + (size_t)rr * DIM + ch * 128 + gk * 8;
            wg[i] = *(const u32x4*)src;
        }
        __syncthreads();   // previous chunk fully consumed
        #pragma unroll
        for (int i = 0; i < 10; ++i) {
            const int lvl = (i >= 5) ? 1 : 0;
            const int gg = tid + i * 256 - lvl * 1280;
            const int rr = gg >> 4, gk = gg & 15;
            *(u32x4*)(w2s + lvl * 10240 + rr * 128 + ((gk ^ (rr & 7)) * 8)) = wg[i];
        }
        __syncthreads();

        // ---- 4 k-steps of MFMA ----
        const int s = arow & 7;
        #pragma unroll
        for (int ks = 0; ks < 4; ++ks) {
            const f32x4 xa = *(const f32x4*)(xrow + ch * 128 + ks * 32);
            const f32x4 xb = *(const f32x4*)(xrow + ch * 128 + ks * 32 + 4);
            const float xf[8] = {xa.x, xa.y, xa.z, xa.w, xb.x, xb.y, xb.z, xb.w};
            _Float16 hh[8], ll[8];
            #pragma unroll
            for (int u = 0; u < 8; ++u) {
                hh[u] = (_Float16)xf[u];
                ll[u] = (_Float16)(xf[u] - (float)hh[u]);
            }
            const half8 ah = {hh[0], hh[1], hh[2], hh[3], hh[4], hh[5], hh[6], hh[7]};
            const half8 al = {ll[0], ll[1], ll[2], ll[3], ll[4], ll[5], ll[6], ll[7]};
            const int Gb = ks * 4 + kg;
            #pragma unroll
            for (int t = 0; t < 5; ++t) {
                const _Float16* bp = w2s + (t * 16 + arow) * 128 + ((Gb ^ s) * 8);
                const half8 bh = *(const half8*)bp;
                const half8 bl = *(const half8*)(bp + 10240);
                acc[t] = MFMA16(ah, bh, acc[t]);
                acc[t] = MFMA16(al, bh, acc[t]);
                acc[t] = MFMA16(ah, bl, acc[t]);
            }
        }
    }

    // ---- in-register softmax + gate (round-2 verbatim, writes to LDS) ----
    float hl[4];
    #pragma unroll
    for (int t = 0; t < 4; ++t) hl[t] = h[t * 16 + arow];
    const float gb = gate_b[0];

    #pragma unroll
    for (int j = 0; j < 4; ++j) {
        float m = fmaxf(fmaxf(acc[0][j], acc[1][j]), fmaxf(acc[2][j], acc[3][j]));
        #pragma unroll
        for (int off = 1; off < 16; off <<= 1) m = fmaxf(m, __shfl_xor(m, off));
        float p[4];
        float sum = 0.f;
        #pragma unroll
        for (int t = 0; t < 4; ++t) { p[t] = __expf((acc[t][j] - m) * TINV); sum += p[t]; }
        #pragma unroll
        for (int off = 1; off < 16; off <<= 1) sum += __shfl_xor(sum, off);
        const float inv = 1.f / sum;
        float gp = 0.f;
        #pragma unroll
        for (int t = 0; t < 4; ++t) {
            const float a = p[t] * inv;
            attn_s[w][kg * 4 + j][t * 16 + arow] = (_Float16)a;
            gp = fmaf(a, hl[t], gp);
        }
        #pragma unroll
        for (int off = 1; off < 16; off <<= 1) gp += __shfl_xor(gp, off);
        const float sg = __shfl(acc[4][j], lane & 48);   // gate col (raw, no TINV)
        if (arow == 0)
            gate_s[w][kg * 4 + j] = 1.f / (1.f + __expf(-(sg + gp + gb)));
    }

    // ---- phase B: retrieve + mix (round-5 verbatim, wave-local source) ----
    // All handoff is wave-local (wave w wrote attn_s[w]/gate_s[w] above);
    // no barrier needed.
    const size_t rbase = row0 + w * 16;
    const half8 a0 = *(const half8*)(&attn_s[w][arow][kg * 8]);
    const half8 a1 = *(const half8*)(&attn_s[w][arow][kg * 8 + 32]);
    const float g = gate_s[w][arow];

    const size_t rowoff = (rbase + arow) * DIM + kg * 4;
    const float* xp = x + rowoff;
    float* op = out + rowoff;
    const _Float16* w3base = W3T + (size_t)arow * NSLOT + kg * 8;

    // 2-deep software pipeline: loads for dt+1 issued before compute of dt
    half8 b0 = *(const half8*)w3base;
    half8 b1 = *(const half8*)(w3base + 32);
    f32x4 xv = *(const f32x4*)xp;

    for (int dt = 0; dt < 128; ++dt) {
        half8 nb0, nb1;
        f32x4 nxv;
        if (dt < 127) {
            const _Float16* bp = w3base + (size_t)(dt + 1) * 16 * NSLOT;
            nb0 = *(const half8*)bp;
            nb1 = *(const half8*)(bp + 32);
            nxv = *(const f32x4*)(xp + (dt + 1) * 16);
        }
        f32x4 r = {0.f, 0.f, 0.f, 0.f};
        r = MFMA16(b0, a0, r);                      // swapped operands (R5-validated)
        r = MFMA16(b1, a1, r);
        f32x4 o;
        o.x = fmaf(g, xv.x - r.x, r.x);
        o.y = fmaf(g, xv.y - r.y, r.y);
        o.z = fmaf(g, xv.z - r.z, r.z);
        o.w = fmaf(g, xv.w - r.w, r.w);
        *(f32x4*)(op + dt * 16) = o;
        b0 = nb0; b1 = nb1; xv = nxv;
    }
}

// ================================ launch ===================================

extern "C" void kernel_launch(void* const* d_in, const int* in_sizes, int n_in,
                              void* d_out, int out_size, void* d_ws, size_t ws_size,
                              hipStream_t stream) {
    (void)in_sizes; (void)n_in; (void)out_size; (void)ws_size;
    const float* x       = (const float*)d_in[0];
    const float* memory  = (const float*)d_in[1];
    const float* key_w   = (const float*)d_in[2];
    const float* value_w = (const float*)d_in[3];
    const float* gate_w  = (const float*)d_in[4];
    const float* gate_b  = (const float*)d_in[5];
    float* out = (float*)d_out;

    char* wsb = (char*)d_ws;                       // needs ~934 KB
    _Float16* W2h  = (_Float16*)(wsb + OFF_W2H);
    _Float16* W2l  = (_Float16*)(wsb + OFF_W2L);
    _Float16* W3T  = (_Float16*)(wsb + OFF_W3T);
    float*    h    = (float*)(wsb + OFF_H);
    float*    tpt  = (float*)(wsb + OFF_TPART);

    prep_w2 <<<dim3(8, 9), 256, 0, stream>>>(memory, key_w, gate_w, W2h, W2l);
    prep_w3t<<<dim3(8, 8), 256, 0, stream>>>(memory, value_w, W3T);
    prep_t  <<<8, 256, 0, stream>>>(value_w, gate_w, tpt);
    prep_h  <<<1, 512, 0, stream>>>(memory, tpt, h);

    fused_kernel<<<512, 256, 0, stream>>>(x, W2h, W2l, W3T, h, gate_b, out);
}

// Round 8
// 322.521 us; speedup vs baseline: 1.1571x; 1.1571x over previous
//
#include <hip/hip_runtime.h>
#include <stdint.h>

#define DIM   2048
#define NSLOT 64
#define MDIM  512
#define TINV  10.0f

typedef __attribute__((ext_vector_type(4))) float     f32x4;
typedef __attribute__((ext_vector_type(8))) _Float16  half8;
typedef __attribute__((ext_vector_type(4))) unsigned int u32x4;

#define MFMA16(a,b,c) __builtin_amdgcn_mfma_f32_16x16x32_f16((a),(b),(c),0,0,0)

// ---------------------------------------------------------------------------
// ws layout (bytes), total ~934 KB (identical to round 6):
//   W2h  [80][2048] f16 : rows 0-63 = memory@key_w, row 64 = gate_w[:2048], 65-79 = 0
//   W2l  [80][2048] f16 : fp16 residual of the above (2-way split)
//   W3T  [2048][64] f16 : W3T[d][n] = sum_m memory[n][m]*value_w[d][m]
//   h    [64] f32       : h[n] = sum_d W3[n][d]*gate_w[DIM+d]
//   tpart[8][512] f32
// ---------------------------------------------------------------------------
#define OFF_W2H   0
#define OFF_W2L   327680
#define OFF_W3T   655360
#define OFF_H     917504
#define OFF_TPART 917760

// ============================ prep kernels =================================
// (byte-identical to rounds 2/4/5/6)

__global__ __launch_bounds__(256) void prep_w2(
    const float* __restrict__ memory, const float* __restrict__ key_w,
    const float* __restrict__ gate_w, _Float16* __restrict__ W2h,
    _Float16* __restrict__ W2l)
{
    const int tid = threadIdx.x;
    const int c = blockIdx.x;      // k-chunk of 256
    const int g = blockIdx.y;      // 0..7 slot groups, 8 = gate row + zero rows
    const int k = c * 256 + tid;

    if (g == 8) {
        float v = gate_w[k];
        _Float16 ph = (_Float16)v;
        _Float16 pl = (_Float16)(v - (float)ph);
        W2h[(size_t)64 * DIM + k] = ph;
        W2l[(size_t)64 * DIM + k] = pl;
        for (int r = 65; r < 80; ++r) {
            W2h[(size_t)r * DIM + k] = (_Float16)0.f;
            W2l[(size_t)r * DIM + k] = (_Float16)0.f;
        }
        return;
    }

    __shared__ __align__(16) float mem_s[8 * MDIM];
    for (int i = tid; i < 8 * MDIM; i += 256)
        mem_s[i] = memory[g * 8 * MDIM + i];
    __syncthreads();

    const f32x4* ms4 = (const f32x4*)mem_s;
    float acc[8] = {};
    for (int m4 = 0; m4 < MDIM / 4; ++m4) {
        const float kw0 = key_w[(size_t)(m4 * 4 + 0) * DIM + k];
        const float kw1 = key_w[(size_t)(m4 * 4 + 1) * DIM + k];
        const float kw2 = key_w[(size_t)(m4 * 4 + 2) * DIM + k];
        const float kw3 = key_w[(size_t)(m4 * 4 + 3) * DIM + k];
        #pragma unroll
        for (int i = 0; i < 8; ++i) {
            const f32x4 mv = ms4[i * (MDIM / 4) + m4];
            acc[i] = fmaf(mv.x, kw0, acc[i]);
            acc[i] = fmaf(mv.y, kw1, acc[i]);
            acc[i] = fmaf(mv.z, kw2, acc[i]);
            acc[i] = fmaf(mv.w, kw3, acc[i]);
        }
    }
    #pragma unroll
    for (int i = 0; i < 8; ++i) {
        float v = acc[i];
        _Float16 ph = (_Float16)v;
        _Float16 pl = (_Float16)(v - (float)ph);
        W2h[(size_t)(g * 8 + i) * DIM + k] = ph;
        W2l[(size_t)(g * 8 + i) * DIM + k] = pl;
    }
}

__global__ __launch_bounds__(256) void prep_w3t(
    const float* __restrict__ memory, const float* __restrict__ value_w,
    _Float16* __restrict__ W3T)
{
    const int tid = threadIdx.x;
    const int c = blockIdx.x;      // d-chunk of 256
    const int g = blockIdx.y;      // slot group of 8
    const int d = c * 256 + tid;

    __shared__ __align__(16) float mem_s[8 * MDIM];
    for (int i = tid; i < 8 * MDIM; i += 256)
        mem_s[i] = memory[g * 8 * MDIM + i];
    __syncthreads();

    const f32x4* ms4 = (const f32x4*)mem_s;
    const f32x4* vp = (const f32x4*)(value_w + (size_t)d * MDIM);
    float acc[8] = {};
    for (int m4 = 0; m4 < MDIM / 4; ++m4) {
        const f32x4 v = vp[m4];
        #pragma unroll
        for (int i = 0; i < 8; ++i) {
            const f32x4 mv = ms4[i * (MDIM / 4) + m4];
            acc[i] = fmaf(mv.x, v.x, acc[i]);
            acc[i] = fmaf(mv.y, v.y, acc[i]);
            acc[i] = fmaf(mv.z, v.z, acc[i]);
            acc[i] = fmaf(mv.w, v.w, acc[i]);
        }
    }
    #pragma unroll
    for (int i = 0; i < 8; ++i)
        W3T[(size_t)d * NSLOT + g * 8 + i] = (_Float16)acc[i];
}

__global__ __launch_bounds__(256) void prep_t(
    const float* __restrict__ value_w, const float* __restrict__ gate_w,
    float* __restrict__ tpart)
{
    const int b = blockIdx.x;      // d-chunk of 256
    const int tid = threadIdx.x;
    float a0 = 0.f, a1 = 0.f;
    for (int d = b * 256; d < b * 256 + 256; ++d) {
        const float gv = gate_w[DIM + d];
        a0 = fmaf(value_w[(size_t)d * MDIM + tid], gv, a0);
        a1 = fmaf(value_w[(size_t)d * MDIM + tid + 256], gv, a1);
    }
    tpart[b * 512 + tid] = a0;
    tpart[b * 512 + tid + 256] = a1;
}

__global__ __launch_bounds__(512) void prep_h(
    const float* __restrict__ memory, const float* __restrict__ tpart,
    float* __restrict__ h)
{
    __shared__ float ts[512];
    const int tid = threadIdx.x;
    float s = 0.f;
    #pragma unroll
    for (int b = 0; b < 8; ++b) s += tpart[b * 512 + tid];
    ts[tid] = s;
    __syncthreads();
    const int lane = tid & 63, w = tid >> 6;
    #pragma unroll
    for (int q = 0; q < 8; ++q) {
        const int n = w * 8 + q;
        float p = 0.f;
        for (int m = lane; m < MDIM; m += 64)
            p = fmaf(memory[(size_t)n * MDIM + m], ts[m], p);
        #pragma unroll
        for (int off = 32; off; off >>= 1) p += __shfl_xor(p, off);
        if (lane == 0) h[n] = p;
    }
}

// ============================ fused kernel =================================
// Round-6 math/indices (validated). Scheduling-only changes vs R6:
//  - Phase A: x fragments double-buffered in registers (xA/xB), loop unrolled
//    x2 so next chunk's 8 global loads issue a full chunk before use.
//  - Phase B: 4-deep static-rotation prefetch (unroll 4, dt&3 slots).
// R7-bug fix: staging restored to 10 granules/thread (st[10], lvl = i>=5) —
// R7's st[5] staged only the W2h level, leaving W2l garbage in LDS.

__global__ __launch_bounds__(256) void fused_kernel(
    const float* __restrict__ x,
    const _Float16* __restrict__ W2h, const _Float16* __restrict__ W2l,
    const _Float16* __restrict__ W3T,
    const float* __restrict__ h, const float* __restrict__ gate_b,
    float* __restrict__ out)
{
    __shared__ __align__(16) _Float16 w2s[2 * 80 * 128];   // 40 KB
    __shared__ __align__(16) _Float16 attn_s[4][16][72];   // 9 KB
    __shared__ float gate_s[4][16];

    const int tid  = threadIdx.x;
    const int lane = tid & 63;
    const int w    = tid >> 6;          // wave = m-tile 0..3
    const int arow = lane & 15;         // A-row / B-row (lane&15)
    const int kg   = lane >> 4;         // k-group
    const size_t row0 = (size_t)blockIdx.x * 64;

    f32x4 acc[5];
    {   f32x4 z = {0.f, 0.f, 0.f, 0.f};
        #pragma unroll
        for (int t = 0; t < 5; ++t) acc[t] = z; }

    const float* xrow = x + (row0 + w * 16 + arow) * DIM + kg * 8;

    // ---- staging helpers: 10 granules/thread, EXACT round-6 addressing ----
    u32x4 st[10];
    auto load_st = [&](int chn) {
        #pragma unroll
        for (int i = 0; i < 10; ++i) {
            const int lvl = (i >= 5) ? 1 : 0;             // uniform per unrolled i
            const int gg = tid + i * 256 - lvl * 1280;    // granule within level
            const int rr = gg >> 4, gk = gg & 15;
            const _Float16* src = (lvl ? W2l : W2h) + (size_t)rr * DIM + chn * 128 + gk * 8;
            st[i] = *(const u32x4*)src;
        }
    };
    auto write_st = [&]() {
        #pragma unroll
        for (int i = 0; i < 10; ++i) {
            const int lvl = (i >= 5) ? 1 : 0;
            const int gg = tid + i * 256 - lvl * 1280;
            const int rr = gg >> 4, gk = gg & 15;
            *(u32x4*)(w2s + lvl * 10240 + rr * 128 + ((gk ^ (rr & 7)) * 8)) = st[i];
        }
    };
    f32x4 xA[8], xB[8];
    auto load_x = [&](f32x4* XB, int chn) {
        #pragma unroll
        for (int ks = 0; ks < 4; ++ks) {
            XB[ks * 2]     = *(const f32x4*)(xrow + chn * 128 + ks * 32);
            XB[ks * 2 + 1] = *(const f32x4*)(xrow + chn * 128 + ks * 32 + 4);
        }
    };
    auto compute_chunk = [&](const f32x4* XB) {
        const int s = arow & 7;
        #pragma unroll
        for (int ks = 0; ks < 4; ++ks) {
            const f32x4 xa = XB[ks * 2];
            const f32x4 xb = XB[ks * 2 + 1];
            const float xf[8] = {xa.x, xa.y, xa.z, xa.w, xb.x, xb.y, xb.z, xb.w};
            _Float16 hh[8], ll[8];
            #pragma unroll
            for (int u = 0; u < 8; ++u) {
                hh[u] = (_Float16)xf[u];
                ll[u] = (_Float16)(xf[u] - (float)hh[u]);
            }
            const half8 ah = {hh[0], hh[1], hh[2], hh[3], hh[4], hh[5], hh[6], hh[7]};
            const half8 al = {ll[0], ll[1], ll[2], ll[3], ll[4], ll[5], ll[6], ll[7]};
            const int Gb = ks * 4 + kg;
            #pragma unroll
            for (int t = 0; t < 5; ++t) {
                const _Float16* bp = w2s + (t * 16 + arow) * 128 + ((Gb ^ s) * 8);
                const half8 bh = *(const half8*)bp;
                const half8 bl = *(const half8*)(bp + 10240);
                acc[t] = MFMA16(ah, bh, acc[t]);
                acc[t] = MFMA16(al, bh, acc[t]);
                acc[t] = MFMA16(ah, bl, acc[t]);
            }
        }
    };

    // ---- phase A main loop: 16 chunks, unrolled x2, x double-buffered ----
    load_st(0);
    load_x(xA, 0);
    for (int chp = 0; chp < 16; chp += 2) {
        __syncthreads();            // everyone done reading w2s (prev chunk)
        write_st();                 // chunk chp into LDS
        __syncthreads();
        load_st(chp + 1);           // W2 prefetch (chp+1 <= 15 always)
        load_x(xB, chp + 1);        // x prefetch for next chunk
        compute_chunk(xA);

        __syncthreads();
        write_st();                 // chunk chp+1 into LDS
        __syncthreads();
        if (chp + 2 < 16) {
            load_st(chp + 2);
            load_x(xA, chp + 2);
        }
        compute_chunk(xB);
    }

    // ---- in-register softmax + gate (round-6 verbatim, writes to LDS) ----
    float hl[4];
    #pragma unroll
    for (int t = 0; t < 4; ++t) hl[t] = h[t * 16 + arow];
    const float gb = gate_b[0];

    #pragma unroll
    for (int j = 0; j < 4; ++j) {
        float m = fmaxf(fmaxf(acc[0][j], acc[1][j]), fmaxf(acc[2][j], acc[3][j]));
        #pragma unroll
        for (int off = 1; off < 16; off <<= 1) m = fmaxf(m, __shfl_xor(m, off));
        float p[4];
        float sum = 0.f;
        #pragma unroll
        for (int t = 0; t < 4; ++t) { p[t] = __expf((acc[t][j] - m) * TINV); sum += p[t]; }
        #pragma unroll
        for (int off = 1; off < 16; off <<= 1) sum += __shfl_xor(sum, off);
        const float inv = 1.f / sum;
        float gp = 0.f;
        #pragma unroll
        for (int t = 0; t < 4; ++t) {
            const float a = p[t] * inv;
            attn_s[w][kg * 4 + j][t * 16 + arow] = (_Float16)a;
            gp = fmaf(a, hl[t], gp);
        }
        #pragma unroll
        for (int off = 1; off < 16; off <<= 1) gp += __shfl_xor(gp, off);
        const float sg = __shfl(acc[4][j], lane & 48);   // gate col (raw, no TINV)
        if (arow == 0)
            gate_s[w][kg * 4 + j] = 1.f / (1.f + __expf(-(sg + gp + gb)));
    }

    // ---- phase B: retrieve + mix (round-6 math, 4-deep prefetch) ----
    const size_t rbase = row0 + w * 16;
    const half8 a0 = *(const half8*)(&attn_s[w][arow][kg * 8]);
    const half8 a1 = *(const half8*)(&attn_s[w][arow][kg * 8 + 32]);
    const float g = gate_s[w][arow];

    const size_t rowoff = (rbase + arow) * DIM + kg * 4;
    const float* xp = x + rowoff;
    float* op = out + rowoff;
    const _Float16* w3base = W3T + (size_t)arow * NSLOT + kg * 8;

    half8 qb0[4], qb1[4];
    f32x4 qx[4];
    #pragma unroll
    for (int s = 0; s < 4; ++s) {
        const _Float16* bp = w3base + (size_t)s * 16 * NSLOT;
        qb0[s] = *(const half8*)bp;
        qb1[s] = *(const half8*)(bp + 32);
        qx[s]  = *(const f32x4*)(xp + s * 16);
    }

    #pragma unroll 4
    for (int dt = 0; dt < 128; ++dt) {
        const int s = dt & 3;                       // static under unroll 4
        f32x4 r = {0.f, 0.f, 0.f, 0.f};
        r = MFMA16(qb0[s], a0, r);                  // swapped operands (validated)
        r = MFMA16(qb1[s], a1, r);
        const f32x4 xv = qx[s];
        int nt = dt + 4; if (nt > 127) nt = 127;    // clamped prefetch
        const _Float16* bp = w3base + (size_t)nt * 16 * NSLOT;
        qb0[s] = *(const half8*)bp;
        qb1[s] = *(const half8*)(bp + 32);
        qx[s]  = *(const f32x4*)(xp + (size_t)nt * 16);
        f32x4 o;
        o.x = fmaf(g, xv.x - r.x, r.x);
        o.y = fmaf(g, xv.y - r.y, r.y);
        o.z = fmaf(g, xv.z - r.z, r.z);
        o.w = fmaf(g, xv.w - r.w, r.w);
        *(f32x4*)(op + dt * 16) = o;
    }
}

// ================================ launch ===================================

extern "C" void kernel_launch(void* const* d_in, const int* in_sizes, int n_in,
                              void* d_out, int out_size, void* d_ws, size_t ws_size,
                              hipStream_t stream) {
    (void)in_sizes; (void)n_in; (void)out_size; (void)ws_size;
    const float* x       = (const float*)d_in[0];
    const float* memory  = (const float*)d_in[1];
    const float* key_w   = (const float*)d_in[2];
    const float* value_w = (const float*)d_in[3];
    const float* gate_w  = (const float*)d_in[4];
    const float* gate_b  = (const float*)d_in[5];
    float* out = (float*)d_out;

    char* wsb = (char*)d_ws;                       // needs ~934 KB
    _Float16* W2h  = (_Float16*)(wsb + OFF_W2H);
    _Float16* W2l  = (_Float16*)(wsb + OFF_W2L);
    _Float16* W3T  = (_Float16*)(wsb + OFF_W3T);
    float*    h    = (float*)(wsb + OFF_H);
    float*    tpt  = (float*)(wsb + OFF_TPART);

    prep_w2 <<<dim3(8, 9), 256, 0, stream>>>(memory, key_w, gate_w, W2h, W2l);
    prep_w3t<<<dim3(8, 8), 256, 0, stream>>>(memory, value_w, W3T);
    prep_t  <<<8, 256, 0, stream>>>(value_w, gate_w, tpt);
    prep_h  <<<1, 512, 0, stream>>>(memory, tpt, h);

    fused_kernel<<<512, 256, 0, stream>>>(x, W2h, W2l, W3T, h, gate_b, out);
}